// Round 2
// baseline (1764.812 us; speedup 1.0000x reference)
//
#include <hip/hip_runtime.h>
#include <hip/hip_bf16.h>
#include <stdint.h>

#define H 4
#define HID 64
#define CDIM 256   /* = H*HID = IN = FC */
#define OUTC 4
#define ALPHA 0.2f
#define NW 16      /* number of float weight inputs (d_in[2..17]) */

// ---------------------------------------------------------------------------
// dtype detection: are the float inputs bf16 or fp32?
// Reads 4096 32-bit words of x; counts low-16-half words whose bf16 exponent
// field is plausible for ~N(0,1) data. bf16 data -> ~4096 hits; fp32 data
// (low half = mantissa garbage) -> ~700 hits. flag=1 means bf16.
// ---------------------------------------------------------------------------
__global__ void detect_k(const uint32_t* __restrict__ xw, int* __restrict__ flag) {
    __shared__ int sd[256];
    int t = threadIdx.x;
    int hits = 0;
    for (int i = 0; i < 16; ++i) {
        uint32_t w = xw[t * 16 + i];
        uint32_t ex = (w >> 7) & 0xffu;   // exponent field of low bf16 half
        if (ex >= 100u && ex <= 145u) hits++;
    }
    sd[t] = hits;
    __syncthreads();
    for (int s = 128; s > 0; s >>= 1) {
        if (t < s) sd[t] += sd[t + s];
        __syncthreads();
    }
    if (t == 0) *flag = (sd[0] > 3000) ? 1 : 0;
}

// ---------------------------------------------------------------------------
// Convert all 16 weight tensors to fp32 in ws (branch on flag).
// ---------------------------------------------------------------------------
struct WPtrs {
    const void* p[NW];
    int sz[NW];
    int off[NW];
};

__global__ void convert_k(WPtrs ptrs, float* __restrict__ outb, const int* __restrict__ flag) {
    int which = blockIdx.y;
    int n = ptrs.sz[which];
    int i = blockIdx.x * 256 + threadIdx.x;
    if (i >= n) return;
    float v;
    if (*flag) v = __bfloat162float(((const __hip_bfloat16*)ptrs.p[which])[i]);
    else       v = ((const float*)ptrs.p[which])[i];
    outb[ptrs.off[which] + i] = v;
}

// ---------------------------------------------------------------------------
// CSR build: histogram -> scan -> scatter
// ---------------------------------------------------------------------------
__global__ void hist_k(const int* __restrict__ srcI, int* __restrict__ counts, int Ee) {
    int e = blockIdx.x * 256 + threadIdx.x;
    if (e < Ee) atomicAdd(&counts[srcI[e]], 1);
}

__global__ void scan1_k(const int* __restrict__ counts, int* __restrict__ bs, int Nn) {
    __shared__ int sd[256];
    int t = threadIdx.x;
    int i = blockIdx.x * 256 + t;
    sd[t] = (i < Nn) ? counts[i] : 0;
    __syncthreads();
    for (int s = 128; s > 0; s >>= 1) {
        if (t < s) sd[t] += sd[t + s];
        __syncthreads();
    }
    if (t == 0) bs[blockIdx.x] = sd[0];
}

__global__ void scan2_k(int* __restrict__ bs, int nb) {
    __shared__ int sd[512];
    int t = threadIdx.x;
    int v = (t < nb) ? bs[t] : 0;
    sd[t] = v;
    __syncthreads();
    for (int offm = 1; offm < 512; offm <<= 1) {
        int add = (t >= offm) ? sd[t - offm] : 0;
        __syncthreads();
        sd[t] += add;
        __syncthreads();
    }
    if (t < nb) bs[t] = sd[t] - v;   // exclusive
}

__global__ void scan3_k(const int* __restrict__ counts, const int* __restrict__ bs,
                        int* __restrict__ rowStart, int* __restrict__ cur, int Nn, int Ee) {
    __shared__ int sd[256];
    int t = threadIdx.x;
    int i = blockIdx.x * 256 + t;
    int v = (i < Nn) ? counts[i] : 0;
    sd[t] = v;
    __syncthreads();
    for (int offm = 1; offm < 256; offm <<= 1) {
        int add = (t >= offm) ? sd[t - offm] : 0;
        __syncthreads();
        sd[t] += add;
        __syncthreads();
    }
    int excl = sd[t] - v + bs[blockIdx.x];
    if (i < Nn) { rowStart[i] = excl; cur[i] = excl; }
    if (i == Nn) rowStart[i] = Ee;
}

__global__ void scatter_k(const int* __restrict__ srcI, const int* __restrict__ dstI,
                          int* __restrict__ cur, int* __restrict__ colI, int Ee) {
    int e = blockIdx.x * 256 + threadIdx.x;
    if (e < Ee) {
        int p = atomicAdd(&cur[srcI[e]], 1);
        colI[p] = dstI[e];
    }
}

// ---------------------------------------------------------------------------
// GEMM: C[M x 256] = A[M x 256] @ B^T, B fp32 [256 x 256] row-major (B[c][k]).
// A_RAW=1: A is the raw input x (bf16 or fp32 per *flag). A_RAW=0: A fp32 ws.
// 64x64 tile / 256 threads, K-tile 32, transposed LDS, 4x4 microkernel.
// ---------------------------------------------------------------------------
template <int A_RAW, int RELU, int BIAS>
__global__ __launch_bounds__(256) void gemm_k(
    const void* __restrict__ Ap, const float* __restrict__ B,
    const float* __restrict__ bias, float* __restrict__ C, int M,
    const int* __restrict__ flagp)
{
    __shared__ __align__(16) float As[32][68];
    __shared__ __align__(16) float Bs[32][68];
    int tid = threadIdx.x;
    int row0 = blockIdx.x * 64;
    int col0 = blockIdx.y * 64;
    int ty = tid >> 4, tx = tid & 15;
    int isbf = A_RAW ? *flagp : 0;
    float acc[4][4] = {};

    for (int k0 = 0; k0 < CDIM; k0 += 32) {
        // --- stage A (transposed: As[k][m]) ---
        if (A_RAW && isbf) {
            const __hip_bfloat16* A = (const __hip_bfloat16*)Ap;
            int r  = tid >> 2;
            int ks = (tid & 3) << 3;
            int grow = row0 + r;
            uint32_t w[4] = {0u, 0u, 0u, 0u};
            if (grow < M) {
                const uint4 q = *(const uint4*)(A + (size_t)grow * CDIM + k0 + ks);
                w[0] = q.x; w[1] = q.y; w[2] = q.z; w[3] = q.w;
            }
            #pragma unroll
            for (int p = 0; p < 4; ++p) {
                As[ks + 2*p][r]     = __uint_as_float((w[p] & 0xffffu) << 16);
                As[ks + 2*p + 1][r] = __uint_as_float(w[p] & 0xffff0000u);
            }
        } else {
            const float* A = (const float*)Ap;
            #pragma unroll
            for (int l = 0; l < 2; ++l) {
                int idx = tid + l * 256;
                int r  = idx >> 3;
                int ks = (idx & 7) << 2;
                int grow = row0 + r;
                float4 f = make_float4(0.f, 0.f, 0.f, 0.f);
                if (grow < M) f = *(const float4*)(A + (size_t)grow * CDIM + k0 + ks);
                As[ks + 0][r] = f.x; As[ks + 1][r] = f.y;
                As[ks + 2][r] = f.z; As[ks + 3][r] = f.w;
            }
        }
        // --- stage B (fp32 converted weights, always in-range 256x256) ---
        {
            #pragma unroll
            for (int l = 0; l < 2; ++l) {
                int idx = tid + l * 256;
                int r  = idx >> 3;
                int ks = (idx & 7) << 2;
                float4 f = *(const float4*)(B + (size_t)(col0 + r) * CDIM + k0 + ks);
                Bs[ks + 0][r] = f.x; Bs[ks + 1][r] = f.y;
                Bs[ks + 2][r] = f.z; Bs[ks + 3][r] = f.w;
            }
        }
        __syncthreads();
        #pragma unroll
        for (int kk = 0; kk < 32; ++kk) {
            const float4 av = *(const float4*)(&As[kk][ty * 4]);
            const float4 bv = *(const float4*)(&Bs[kk][tx * 4]);
            const float a_[4] = {av.x, av.y, av.z, av.w};
            const float b_[4] = {bv.x, bv.y, bv.z, bv.w};
            #pragma unroll
            for (int i = 0; i < 4; ++i)
                #pragma unroll
                for (int j = 0; j < 4; ++j)
                    acc[i][j] = fmaf(a_[i], b_[j], acc[i][j]);
        }
        __syncthreads();
    }
    #pragma unroll
    for (int i = 0; i < 4; ++i) {
        int row = row0 + ty * 4 + i;
        if (row < M) {
            float4 v;
            float* vp = &v.x;
            #pragma unroll
            for (int j = 0; j < 4; ++j) {
                float t = acc[i][j];
                if constexpr (BIAS) t += bias[col0 + tx * 4 + j];
                if constexpr (RELU) t = fmaxf(t, 0.f);
                vp[j] = t;
            }
            *(float4*)(C + (size_t)row * CDIM + col0 + tx * 4) = v;
        }
    }
}

// ---------------------------------------------------------------------------
// Per-node attention scores. Block=256 = one node; wave w handles head w.
// ---------------------------------------------------------------------------
__global__ __launch_bounds__(256) void scores_k(
    const float* __restrict__ h,
    const float* __restrict__ a1w, const float* __restrict__ a1bias,
    const float* __restrict__ a2w, const float* __restrict__ a2bias,
    float* __restrict__ a1, float* __restrict__ a2)
{
    int n = blockIdx.x;
    int t = threadIdx.x;
    int head = t >> 6, d = t & 63;
    float hv = h[(size_t)n * CDIM + t];
    float s1 = hv * a1w[t];
    float s2 = hv * a2w[t];
    #pragma unroll
    for (int off = 32; off > 0; off >>= 1) {
        s1 += __shfl_xor(s1, off);
        s2 += __shfl_xor(s2, off);
    }
    if (d == 0) {
        a1[(size_t)n * H + head] = s1 + a1bias[head];
        a2[(size_t)n * H + head] = s2 + a2bias[head];
    }
}

// ---------------------------------------------------------------------------
// Edge aggregation per node (block=256 = one node, t = head*64+d).
// ---------------------------------------------------------------------------
__global__ __launch_bounds__(256) void agg_k(
    const float* __restrict__ h, const float* __restrict__ a1, const float* __restrict__ a2,
    const int* __restrict__ rowStart, const int* __restrict__ colI,
    const float* __restrict__ bias, float* __restrict__ outp, int relu)
{
    int n = blockIdx.x;
    int t = threadIdx.x;
    int head = t >> 6;
    float a1n = a1[(size_t)n * H + head];
    int s = rowStart[n], e = rowStart[n + 1];
    float acc = 0.f, den = 0.f;
    for (int k = s; k < e; ++k) {
        int d = colI[k];
        float z = a1n + a2[(size_t)d * H + head];
        z = (z > 0.f) ? z : ALPHA * z;
        float sv = __expf(z);
        den += sv;
        acc = fmaf(sv, h[(size_t)d * CDIM + t], acc);
    }
    den = (den > 0.f) ? den : 1.f;   // diagnostic guard: finite instead of NaN
    float r = acc / den + bias[t];
    if (relu) r = fmaxf(r, 0.f);
    outp[(size_t)n * CDIM + t] = r;
}

// ---------------------------------------------------------------------------
// Classifier: one wave per node; output dtype chosen by flag (bf16 vs fp32).
// ---------------------------------------------------------------------------
__global__ __launch_bounds__(256) void cls_k(
    const float* __restrict__ feat, const float* __restrict__ Wcls,
    const float* __restrict__ bcls, void* __restrict__ out, int Nn,
    const int* __restrict__ flagp)
{
    int gtid = blockIdx.x * 256 + threadIdx.x;
    int n = gtid >> 6;
    int lane = threadIdx.x & 63;
    if (n >= Nn) return;
    const float* f = feat + (size_t)n * CDIM;
    float p0 = 0.f, p1 = 0.f, p2 = 0.f, p3 = 0.f;
    for (int k = lane; k < CDIM; k += 64) {
        float fv = f[k];
        p0 = fmaf(fv, Wcls[0 * CDIM + k], p0);
        p1 = fmaf(fv, Wcls[1 * CDIM + k], p1);
        p2 = fmaf(fv, Wcls[2 * CDIM + k], p2);
        p3 = fmaf(fv, Wcls[3 * CDIM + k], p3);
    }
    #pragma unroll
    for (int off = 32; off > 0; off >>= 1) {
        p0 += __shfl_xor(p0, off);
        p1 += __shfl_xor(p1, off);
        p2 += __shfl_xor(p2, off);
        p3 += __shfl_xor(p3, off);
    }
    if (lane < OUTC) {
        float pv = (lane == 0) ? p0 : (lane == 1) ? p1 : (lane == 2) ? p2 : p3;
        pv += bcls[lane];
        if (*flagp) ((__hip_bfloat16*)out)[(size_t)n * OUTC + lane] = __float2bfloat16(pv);
        else        ((float*)out)[(size_t)n * OUTC + lane] = pv;
    }
}

// ---------------------------------------------------------------------------
extern "C" void kernel_launch(void* const* d_in, const int* in_sizes, int n_in,
                              void* d_out, int out_size, void* d_ws, size_t ws_size,
                              hipStream_t stream)
{
    const void* x  = d_in[0];
    const int*  ei = (const int*)d_in[1];

    const int Nn = in_sizes[0] / CDIM;   // 100000
    const int Ee = in_sizes[1] / 2;      // 1600000
    const int* srcI = ei;
    const int* dstI = ei + Ee;

    char* wsp = (char*)d_ws;
    size_t off = 0;
    auto alloc = [&](size_t bytes) -> void* {
        void* p = wsp + off;
        off += (bytes + 255) & ~(size_t)255;
        return p;
    };
    float* bufA      = (float*)alloc((size_t)Nn * CDIM * 4);  // 102.4 MB
    float* bufB      = (float*)alloc((size_t)Nn * CDIM * 4);  // 102.4 MB
    float* a1v       = (float*)alloc((size_t)Nn * H * 4);
    float* a2v       = (float*)alloc((size_t)Nn * H * 4);
    int*   rowStart  = (int*)alloc((size_t)(Nn + 1) * 4);
    int*   cursor    = (int*)alloc((size_t)Nn * 4);
    int*   colI      = (int*)alloc((size_t)Ee * 4);           // 6.4 MB
    int*   blockSums = (int*)alloc(512 * 4);
    int*   flag      = (int*)alloc(256);
    float* wconv     = (float*)alloc((size_t)200000 * 4);     // fp32 weights
    (void)ws_size; (void)n_in; (void)out_size;

    // dtype detect + weight conversion
    detect_k<<<1, 256, 0, stream>>>((const uint32_t*)x, flag);
    WPtrs wp;
    int woff = 0;
    for (int i = 0; i < NW; ++i) {
        wp.p[i] = d_in[2 + i];
        wp.sz[i] = in_sizes[2 + i];
        wp.off[i] = woff;
        woff += in_sizes[2 + i];
    }
    {
        dim3 cgrid(256, NW);   // max weight = 65536 elems = 256 blocks
        convert_k<<<cgrid, 256, 0, stream>>>(wp, wconv, flag);
    }
    const float* W1f   = wconv + wp.off[0];
    const float* a11wf = wconv + wp.off[1];
    const float* a11bf = wconv + wp.off[2];
    const float* a12wf = wconv + wp.off[3];
    const float* a12bf = wconv + wp.off[4];
    const float* b1f   = wconv + wp.off[5];
    const float* W2f   = wconv + wp.off[6];
    const float* a21wf = wconv + wp.off[7];
    const float* a21bf = wconv + wp.off[8];
    const float* a22wf = wconv + wp.off[9];
    const float* a22bf = wconv + wp.off[10];
    const float* b2f   = wconv + wp.off[11];
    const float* Wcf   = wconv + wp.off[12];
    const float* bcf   = wconv + wp.off[13];
    const float* Wclsf = wconv + wp.off[14];
    const float* bclsf = wconv + wp.off[15];

    const int NB = (Nn + 255) / 256;   // 391 (fits scan2's 512)
    const int EB = (Ee + 255) / 256;

    // CSR build
    hipMemsetAsync(cursor, 0, (size_t)Nn * 4, stream);
    hist_k<<<EB, 256, 0, stream>>>(srcI, cursor, Ee);
    scan1_k<<<NB, 256, 0, stream>>>(cursor, blockSums, Nn);
    scan2_k<<<1, 512, 0, stream>>>(blockSums, NB);
    scan3_k<<<NB, 256, 0, stream>>>(cursor, blockSums, rowStart, cursor, Nn, Ee);
    scatter_k<<<EB, 256, 0, stream>>>(srcI, dstI, cursor, colI, Ee);

    dim3 ggrid((Nn + 63) / 64, CDIM / 64);

    // Layer 1
    gemm_k<1, 0, 0><<<ggrid, 256, 0, stream>>>(x, W1f, nullptr, bufA, Nn, flag);
    scores_k<<<Nn, 256, 0, stream>>>(bufA, a11wf, a11bf, a12wf, a12bf, a1v, a2v);
    agg_k<<<Nn, 256, 0, stream>>>(bufA, a1v, a2v, rowStart, colI, b1f, bufB, 1);

    // Layer 2
    gemm_k<0, 0, 0><<<ggrid, 256, 0, stream>>>(bufB, W2f, nullptr, bufA, Nn, flag);
    scores_k<<<Nn, 256, 0, stream>>>(bufA, a21wf, a21bf, a22wf, a22bf, a1v, a2v);
    agg_k<<<Nn, 256, 0, stream>>>(bufA, a1v, a2v, rowStart, colI, b2f, bufB, 0);

    // Collator + classifier
    gemm_k<0, 1, 1><<<ggrid, 256, 0, stream>>>(bufB, Wcf, bcf, bufA, Nn, flag);
    cls_k<<<(Nn * 64 + 255) / 256, 256, 0, stream>>>(bufA, Wclsf, bclsf,
                                                     d_out, Nn, flag);
}

// Round 4
// 1740.775 us; speedup vs baseline: 1.0138x; 1.0138x over previous
//
#include <hip/hip_runtime.h>
#include <hip/hip_bf16.h>
#include <hip/hip_fp16.h>
#include <stdint.h>

#define H 4
#define HID 64
#define CDIM 256   /* = H*HID = IN = FC */
#define OUTC 4
#define ALPHA 0.2f
#define NW 16      /* number of float weight inputs (d_in[2..17]) */

// ---------------------------------------------------------------------------
// dtype detection: are the float inputs bf16 or fp32? (R2-proven; real answer
// on this harness: fp32, flag=0 — machinery kept because it passed.)
// ---------------------------------------------------------------------------
__global__ void detect_k(const uint32_t* __restrict__ xw, int* __restrict__ flag) {
    __shared__ int sd[256];
    int t = threadIdx.x;
    int hits = 0;
    for (int i = 0; i < 16; ++i) {
        uint32_t w = xw[t * 16 + i];
        uint32_t ex = (w >> 7) & 0xffu;   // exponent field of low bf16 half
        if (ex >= 100u && ex <= 145u) hits++;
    }
    sd[t] = hits;
    __syncthreads();
    for (int s = 128; s > 0; s >>= 1) {
        if (t < s) sd[t] += sd[t + s];
        __syncthreads();
    }
    if (t == 0) *flag = (sd[0] > 3000) ? 1 : 0;
}

// ---------------------------------------------------------------------------
// Convert all 16 weight tensors to fp32 in ws (branch on flag).
// ---------------------------------------------------------------------------
struct WPtrs {
    const void* p[NW];
    int sz[NW];
    int off[NW];
};

__global__ void convert_k(WPtrs ptrs, float* __restrict__ outb, const int* __restrict__ flag) {
    int which = blockIdx.y;
    int n = ptrs.sz[which];
    int i = blockIdx.x * 256 + threadIdx.x;
    if (i >= n) return;
    float v;
    if (*flag) v = __bfloat162float(((const __hip_bfloat16*)ptrs.p[which])[i]);
    else       v = ((const float*)ptrs.p[which])[i];
    outb[ptrs.off[which] + i] = v;
}

// ---------------------------------------------------------------------------
// CSR build: histogram -> scan -> scatter
// ---------------------------------------------------------------------------
__global__ void hist_k(const int* __restrict__ srcI, int* __restrict__ counts, int Ee) {
    int e = blockIdx.x * 256 + threadIdx.x;
    if (e < Ee) atomicAdd(&counts[srcI[e]], 1);
}

__global__ void scan1_k(const int* __restrict__ counts, int* __restrict__ bs, int Nn) {
    __shared__ int sd[256];
    int t = threadIdx.x;
    int i = blockIdx.x * 256 + t;
    sd[t] = (i < Nn) ? counts[i] : 0;
    __syncthreads();
    for (int s = 128; s > 0; s >>= 1) {
        if (t < s) sd[t] += sd[t + s];
        __syncthreads();
    }
    if (t == 0) bs[blockIdx.x] = sd[0];
}

__global__ void scan2_k(int* __restrict__ bs, int nb) {
    __shared__ int sd[512];
    int t = threadIdx.x;
    int v = (t < nb) ? bs[t] : 0;
    sd[t] = v;
    __syncthreads();
    for (int offm = 1; offm < 512; offm <<= 1) {
        int add = (t >= offm) ? sd[t - offm] : 0;
        __syncthreads();
        sd[t] += add;
        __syncthreads();
    }
    if (t < nb) bs[t] = sd[t] - v;   // exclusive
}

__global__ void scan3_k(const int* __restrict__ counts, const int* __restrict__ bs,
                        int* __restrict__ rowStart, int* __restrict__ cur, int Nn, int Ee) {
    __shared__ int sd[256];
    int t = threadIdx.x;
    int i = blockIdx.x * 256 + t;
    int v = (i < Nn) ? counts[i] : 0;
    sd[t] = v;
    __syncthreads();
    for (int offm = 1; offm < 256; offm <<= 1) {
        int add = (t >= offm) ? sd[t - offm] : 0;
        __syncthreads();
        sd[t] += add;
        __syncthreads();
    }
    int excl = sd[t] - v + bs[blockIdx.x];
    if (i < Nn) { rowStart[i] = excl; cur[i] = excl; }
    if (i == Nn) rowStart[i] = Ee;
}

__global__ void scatter_k(const int* __restrict__ srcI, const int* __restrict__ dstI,
                          int* __restrict__ cur, int* __restrict__ colI, int Ee) {
    int e = blockIdx.x * 256 + threadIdx.x;
    if (e < Ee) {
        int p = atomicAdd(&cur[srcI[e]], 1);
        colI[p] = dstI[e];
    }
}

// ---------------------------------------------------------------------------
// Cast fp32 feature map -> fp16 (for the L3-resident gather table / h storage)
// ---------------------------------------------------------------------------
__global__ void cast_k(const float* __restrict__ in, __half* __restrict__ out, int n4) {
    int i = blockIdx.x * 256 + threadIdx.x;
    if (i >= n4) return;
    const float4 f = ((const float4*)in)[i];
    ushort4 u = make_ushort4(__half_as_ushort(__float2half(f.x)),
                             __half_as_ushort(__float2half(f.y)),
                             __half_as_ushort(__float2half(f.z)),
                             __half_as_ushort(__float2half(f.w)));
    ((ushort4*)out)[i] = u;
}

// ---------------------------------------------------------------------------
// GEMM: C[M x 256] = A[M x 256] @ B^T, B fp32 [256 x 256] row-major (B[c][k]).
// AMODE 0: A is the raw input x (bf16 or fp32 per *flag). AMODE 1: A fp16 ws.
// 64x64 tile / 256 threads, K-tile 32, transposed LDS, 4x4 microkernel.
// ---------------------------------------------------------------------------
template <int AMODE, int RELU, int BIAS>
__global__ __launch_bounds__(256) void gemm_k(
    const void* __restrict__ Ap, const float* __restrict__ B,
    const float* __restrict__ bias, float* __restrict__ C, int M,
    const int* __restrict__ flagp)
{
    __shared__ __align__(16) float As[32][68];
    __shared__ __align__(16) float Bs[32][68];
    int tid = threadIdx.x;
    int row0 = blockIdx.x * 64;
    int col0 = blockIdx.y * 64;
    int ty = tid >> 4, tx = tid & 15;
    int isbf = (AMODE == 0) ? *flagp : 0;
    float acc[4][4] = {};

    for (int k0 = 0; k0 < CDIM; k0 += 32) {
        // --- stage A (transposed: As[k][m]) ---
        if constexpr (AMODE == 1) {
            const __half* A = (const __half*)Ap;
            int r  = tid >> 2;
            int ks = (tid & 3) << 3;
            int grow = row0 + r;
            uint4 q = make_uint4(0u, 0u, 0u, 0u);
            if (grow < M) q = *(const uint4*)(A + (size_t)grow * CDIM + k0 + ks);
            const __half2* hw = (const __half2*)&q;
            #pragma unroll
            for (int p = 0; p < 4; ++p) {
                float2 f = __half22float2(hw[p]);
                As[ks + 2*p][r]     = f.x;
                As[ks + 2*p + 1][r] = f.y;
            }
        } else if (isbf) {
            const __hip_bfloat16* A = (const __hip_bfloat16*)Ap;
            int r  = tid >> 2;
            int ks = (tid & 3) << 3;
            int grow = row0 + r;
            uint32_t w[4] = {0u, 0u, 0u, 0u};
            if (grow < M) {
                const uint4 q = *(const uint4*)(A + (size_t)grow * CDIM + k0 + ks);
                w[0] = q.x; w[1] = q.y; w[2] = q.z; w[3] = q.w;
            }
            #pragma unroll
            for (int p = 0; p < 4; ++p) {
                As[ks + 2*p][r]     = __uint_as_float((w[p] & 0xffffu) << 16);
                As[ks + 2*p + 1][r] = __uint_as_float(w[p] & 0xffff0000u);
            }
        } else {
            const float* A = (const float*)Ap;
            #pragma unroll
            for (int l = 0; l < 2; ++l) {
                int idx = tid + l * 256;
                int r  = idx >> 3;
                int ks = (idx & 7) << 2;
                int grow = row0 + r;
                float4 f = make_float4(0.f, 0.f, 0.f, 0.f);
                if (grow < M) f = *(const float4*)(A + (size_t)grow * CDIM + k0 + ks);
                As[ks + 0][r] = f.x; As[ks + 1][r] = f.y;
                As[ks + 2][r] = f.z; As[ks + 3][r] = f.w;
            }
        }
        // --- stage B (fp32 converted weights, always in-range 256x256) ---
        {
            #pragma unroll
            for (int l = 0; l < 2; ++l) {
                int idx = tid + l * 256;
                int r  = idx >> 3;
                int ks = (idx & 7) << 2;
                float4 f = *(const float4*)(B + (size_t)(col0 + r) * CDIM + k0 + ks);
                Bs[ks + 0][r] = f.x; Bs[ks + 1][r] = f.y;
                Bs[ks + 2][r] = f.z; Bs[ks + 3][r] = f.w;
            }
        }
        __syncthreads();
        #pragma unroll
        for (int kk = 0; kk < 32; ++kk) {
            const float4 av = *(const float4*)(&As[kk][ty * 4]);
            const float4 bv = *(const float4*)(&Bs[kk][tx * 4]);
            const float a_[4] = {av.x, av.y, av.z, av.w};
            const float b_[4] = {bv.x, bv.y, bv.z, bv.w};
            #pragma unroll
            for (int i = 0; i < 4; ++i)
                #pragma unroll
                for (int j = 0; j < 4; ++j)
                    acc[i][j] = fmaf(a_[i], b_[j], acc[i][j]);
        }
        __syncthreads();
    }
    #pragma unroll
    for (int i = 0; i < 4; ++i) {
        int row = row0 + ty * 4 + i;
        if (row < M) {
            float4 v;
            float* vp = &v.x;
            #pragma unroll
            for (int j = 0; j < 4; ++j) {
                float t = acc[i][j];
                if constexpr (BIAS) t += bias[col0 + tx * 4 + j];
                if constexpr (RELU) t = fmaxf(t, 0.f);
                vp[j] = t;
            }
            *(float4*)(C + (size_t)row * CDIM + col0 + tx * 4) = v;
        }
    }
}

// ---------------------------------------------------------------------------
// Per-node attention scores. Block=256 = one node; wave w handles head w.
// ---------------------------------------------------------------------------
__global__ __launch_bounds__(256) void scores_k(
    const float* __restrict__ h,
    const float* __restrict__ a1w, const float* __restrict__ a1bias,
    const float* __restrict__ a2w, const float* __restrict__ a2bias,
    float* __restrict__ a1, float* __restrict__ a2)
{
    int n = blockIdx.x;
    int t = threadIdx.x;
    int head = t >> 6, d = t & 63;
    float hv = h[(size_t)n * CDIM + t];
    float s1 = hv * a1w[t];
    float s2 = hv * a2w[t];
    #pragma unroll
    for (int off = 32; off > 0; off >>= 1) {
        s1 += __shfl_xor(s1, off);
        s2 += __shfl_xor(s2, off);
    }
    if (d == 0) {
        a1[(size_t)n * H + head] = s1 + a1bias[head];
        a2[(size_t)n * H + head] = s2 + a2bias[head];
    }
}

// ---------------------------------------------------------------------------
// Edge aggregation per node (block=256 = one node, t = head*64+d).
// Gathers h rows from the fp16 table (L3-resident); writes h-out as fp16.
// ---------------------------------------------------------------------------
__global__ __launch_bounds__(256) void agg_k(
    const __half* __restrict__ h, const float* __restrict__ a1, const float* __restrict__ a2,
    const int* __restrict__ rowStart, const int* __restrict__ colI,
    const float* __restrict__ bias, __half* __restrict__ outp, int relu)
{
    int n = blockIdx.x;
    int t = threadIdx.x;
    int head = t >> 6;
    float a1n = a1[(size_t)n * H + head];
    int s = rowStart[n], e = rowStart[n + 1];
    float acc = 0.f, den = 0.f;
    for (int k = s; k < e; ++k) {
        int d = colI[k];
        float z = a1n + a2[(size_t)d * H + head];
        z = (z > 0.f) ? z : ALPHA * z;
        float sv = __expf(z);
        den += sv;
        acc = fmaf(sv, __half2float(h[(size_t)d * CDIM + t]), acc);
    }
    den = (den > 0.f) ? den : 1.f;   // diagnostic guard: finite instead of NaN
    float r = acc / den + bias[t];
    if (relu) r = fmaxf(r, 0.f);
    outp[(size_t)n * CDIM + t] = __float2half(r);
}

// ---------------------------------------------------------------------------
// Classifier: one wave per node; output dtype chosen by flag (bf16 vs fp32).
// ---------------------------------------------------------------------------
__global__ __launch_bounds__(256) void cls_k(
    const float* __restrict__ feat, const float* __restrict__ Wcls,
    const float* __restrict__ bcls, void* __restrict__ out, int Nn,
    const int* __restrict__ flagp)
{
    int gtid = blockIdx.x * 256 + threadIdx.x;
    int n = gtid >> 6;
    int lane = threadIdx.x & 63;
    if (n >= Nn) return;
    const float* f = feat + (size_t)n * CDIM;
    float p0 = 0.f, p1 = 0.f, p2 = 0.f, p3 = 0.f;
    for (int k = lane; k < CDIM; k += 64) {
        float fv = f[k];
        p0 = fmaf(fv, Wcls[0 * CDIM + k], p0);
        p1 = fmaf(fv, Wcls[1 * CDIM + k], p1);
        p2 = fmaf(fv, Wcls[2 * CDIM + k], p2);
        p3 = fmaf(fv, Wcls[3 * CDIM + k], p3);
    }
    #pragma unroll
    for (int off = 32; off > 0; off >>= 1) {
        p0 += __shfl_xor(p0, off);
        p1 += __shfl_xor(p1, off);
        p2 += __shfl_xor(p2, off);
        p3 += __shfl_xor(p3, off);
    }
    if (lane < OUTC) {
        float pv = (lane == 0) ? p0 : (lane == 1) ? p1 : (lane == 2) ? p2 : p3;
        pv += bcls[lane];
        if (*flagp) ((__hip_bfloat16*)out)[(size_t)n * OUTC + lane] = __float2bfloat16(pv);
        else        ((float*)out)[(size_t)n * OUTC + lane] = pv;
    }
}

// ---------------------------------------------------------------------------
extern "C" void kernel_launch(void* const* d_in, const int* in_sizes, int n_in,
                              void* d_out, int out_size, void* d_ws, size_t ws_size,
                              hipStream_t stream)
{
    const void* x  = d_in[0];
    const int*  ei = (const int*)d_in[1];

    const int Nn = in_sizes[0] / CDIM;   // 100000
    const int Ee = in_sizes[1] / 2;      // 1600000
    const int* srcI = ei;
    const int* dstI = ei + Ee;

    char* wsp = (char*)d_ws;
    size_t off = 0;
    auto alloc = [&](size_t bytes) -> void* {
        void* p = wsp + off;
        off += (bytes + 255) & ~(size_t)255;
        return p;
    };
    float*  bufA      = (float*)alloc((size_t)Nn * CDIM * 4);   // 102.4 MB fp32 gemm out
    __half* hGa       = (__half*)alloc((size_t)Nn * CDIM * 2);  // 51.2 MB fp16 gather table
    __half* hGb       = (__half*)alloc((size_t)Nn * CDIM * 2);  // 51.2 MB fp16 h1/h2
    float*  a1v       = (float*)alloc((size_t)Nn * H * 4);
    float*  a2v       = (float*)alloc((size_t)Nn * H * 4);
    int*    rowStart  = (int*)alloc((size_t)(Nn + 1) * 4);
    int*    cursor    = (int*)alloc((size_t)Nn * 4);
    int*    colI      = (int*)alloc((size_t)Ee * 4);            // 6.4 MB
    int*    blockSums = (int*)alloc(512 * 4);
    int*    flag      = (int*)alloc(256);
    float*  wconv     = (float*)alloc((size_t)200000 * 4);      // fp32 weights
    (void)ws_size; (void)n_in; (void)out_size;

    // dtype detect + weight conversion (R2-proven; flag=0 on this harness)
    detect_k<<<1, 256, 0, stream>>>((const uint32_t*)x, flag);
    WPtrs wp;
    int woff = 0;
    for (int i = 0; i < NW; ++i) {
        wp.p[i] = d_in[2 + i];
        wp.sz[i] = in_sizes[2 + i];
        wp.off[i] = woff;
        woff += in_sizes[2 + i];
    }
    {
        dim3 cgrid(256, NW);   // max weight = 65536 elems = 256 blocks
        convert_k<<<cgrid, 256, 0, stream>>>(wp, wconv, flag);
    }
    const float* W1f   = wconv + wp.off[0];
    const float* a11wf = wconv + wp.off[1];
    const float* a11bf = wconv + wp.off[2];
    const float* a12wf = wconv + wp.off[3];
    const float* a12bf = wconv + wp.off[4];
    const float* b1f   = wconv + wp.off[5];
    const float* W2f   = wconv + wp.off[6];
    const float* a21wf = wconv + wp.off[7];
    const float* a21bf = wconv + wp.off[8];
    const float* a22wf = wconv + wp.off[9];
    const float* a22bf = wconv + wp.off[10];
    const float* b2f   = wconv + wp.off[11];
    const float* Wcf   = wconv + wp.off[12];
    const float* bcf   = wconv + wp.off[13];
    const float* Wclsf = wconv + wp.off[14];
    const float* bclsf = wconv + wp.off[15];

    const int NB = (Nn + 255) / 256;   // 391 (fits scan2's 512)
    const int EB = (Ee + 255) / 256;
    const int C4 = (Nn * CDIM / 4 + 255) / 256;  // cast grid (25.6M/4 elems)

    // CSR build
    hipMemsetAsync(cursor, 0, (size_t)Nn * 4, stream);
    hist_k<<<EB, 256, 0, stream>>>(srcI, cursor, Ee);
    scan1_k<<<NB, 256, 0, stream>>>(cursor, blockSums, Nn);
    scan2_k<<<1, 512, 0, stream>>>(blockSums, NB);
    scan3_k<<<NB, 256, 0, stream>>>(cursor, blockSums, rowStart, cursor, Nn, Ee);
    scatter_k<<<EB, 256, 0, stream>>>(srcI, dstI, cursor, colI, Ee);

    dim3 ggrid((Nn + 63) / 64, CDIM / 64);

    // Layer 1: gemm(raw x) -> bufA; scores; cast to fp16; aggregate -> hGb
    gemm_k<0, 0, 0><<<ggrid, 256, 0, stream>>>(x, W1f, nullptr, bufA, Nn, flag);
    scores_k<<<Nn, 256, 0, stream>>>(bufA, a11wf, a11bf, a12wf, a12bf, a1v, a2v);
    cast_k<<<C4, 256, 0, stream>>>(bufA, hGa, Nn * CDIM / 4);
    agg_k<<<Nn, 256, 0, stream>>>(hGa, a1v, a2v, rowStart, colI, b1f, hGb, 1);

    // Layer 2: gemm(fp16 h1) -> bufA; scores; cast; aggregate -> hGb
    gemm_k<1, 0, 0><<<ggrid, 256, 0, stream>>>(hGb, W2f, nullptr, bufA, Nn, flag);
    scores_k<<<Nn, 256, 0, stream>>>(bufA, a21wf, a21bf, a22wf, a22bf, a1v, a2v);
    cast_k<<<C4, 256, 0, stream>>>(bufA, hGa, Nn * CDIM / 4);
    agg_k<<<Nn, 256, 0, stream>>>(hGa, a1v, a2v, rowStart, colI, b2f, hGb, 0);

    // Collator (fp16 h2 in, fp32 feat out) + classifier
    gemm_k<1, 1, 1><<<ggrid, 256, 0, stream>>>(hGb, Wcf, bcf, bufA, Nn, flag);
    cls_k<<<(Nn * 64 + 255) / 256, 256, 0, stream>>>(bufA, Wclsf, bclsf,
                                                     d_out, Nn, flag);
}

// Round 5
// 1054.030 us; speedup vs baseline: 1.6743x; 1.6515x over previous
//
#include <hip/hip_runtime.h>
#include <hip/hip_bf16.h>
#include <hip/hip_fp16.h>
#include <stdint.h>

#define H 4
#define HID 64
#define CDIM 256   /* = H*HID = IN = FC */
#define OUTC 4
#define ALPHA 0.2f
#define NW 16      /* number of float weight inputs (d_in[2..17]) */

typedef __attribute__((ext_vector_type(8))) _Float16 f16x8;
typedef __attribute__((ext_vector_type(4))) float f32x4;

// ---------------------------------------------------------------------------
// dtype detection (R2/R4-proven; real answer on this harness: fp32, flag=0)
// ---------------------------------------------------------------------------
__global__ void detect_k(const uint32_t* __restrict__ xw, int* __restrict__ flag) {
    __shared__ int sd[256];
    int t = threadIdx.x;
    int hits = 0;
    for (int i = 0; i < 16; ++i) {
        uint32_t w = xw[t * 16 + i];
        uint32_t ex = (w >> 7) & 0xffu;
        if (ex >= 100u && ex <= 145u) hits++;
    }
    sd[t] = hits;
    __syncthreads();
    for (int s = 128; s > 0; s >>= 1) {
        if (t < s) sd[t] += sd[t + s];
        __syncthreads();
    }
    if (t == 0) *flag = (sd[0] > 3000) ? 1 : 0;
}

// ---------------------------------------------------------------------------
// Convert all 16 weight tensors to fp32 AND fp16 in ws (branch on flag).
// ---------------------------------------------------------------------------
struct WPtrs {
    const void* p[NW];
    int sz[NW];
    int off[NW];
};

__global__ void convert_k(WPtrs ptrs, float* __restrict__ outf, __half* __restrict__ outh,
                          const int* __restrict__ flag) {
    int which = blockIdx.y;
    int n = ptrs.sz[which];
    int i = blockIdx.x * 256 + threadIdx.x;
    if (i >= n) return;
    float v;
    if (*flag) v = __bfloat162float(((const __hip_bfloat16*)ptrs.p[which])[i]);
    else       v = ((const float*)ptrs.p[which])[i];
    outf[ptrs.off[which] + i] = v;
    outh[ptrs.off[which] + i] = __float2half(v);
}

// ---------------------------------------------------------------------------
// Cast x -> fp16 (dual path per flag). 4 elems/thread.
// ---------------------------------------------------------------------------
__global__ void castx_k(const void* __restrict__ x, __half* __restrict__ out,
                        const int* __restrict__ flag, int n4) {
    int i = blockIdx.x * 256 + threadIdx.x;
    if (i >= n4) return;
    ushort4 u;
    if (*flag) {
        uint2 w = ((const uint2*)x)[i];
        float f0 = __uint_as_float((w.x & 0xffffu) << 16);
        float f1 = __uint_as_float(w.x & 0xffff0000u);
        float f2 = __uint_as_float((w.y & 0xffffu) << 16);
        float f3 = __uint_as_float(w.y & 0xffff0000u);
        u = make_ushort4(__half_as_ushort(__float2half(f0)), __half_as_ushort(__float2half(f1)),
                         __half_as_ushort(__float2half(f2)), __half_as_ushort(__float2half(f3)));
    } else {
        float4 f = ((const float4*)x)[i];
        u = make_ushort4(__half_as_ushort(__float2half(f.x)), __half_as_ushort(__float2half(f.y)),
                         __half_as_ushort(__float2half(f.z)), __half_as_ushort(__float2half(f.w)));
    }
    ((ushort4*)out)[i] = u;
}

// ---------------------------------------------------------------------------
// CSR build: histogram -> scan -> scatter
// ---------------------------------------------------------------------------
__global__ void hist_k(const int* __restrict__ srcI, int* __restrict__ counts, int Ee) {
    int e = blockIdx.x * 256 + threadIdx.x;
    if (e < Ee) atomicAdd(&counts[srcI[e]], 1);
}

__global__ void scan1_k(const int* __restrict__ counts, int* __restrict__ bs, int Nn) {
    __shared__ int sd[256];
    int t = threadIdx.x;
    int i = blockIdx.x * 256 + t;
    sd[t] = (i < Nn) ? counts[i] : 0;
    __syncthreads();
    for (int s = 128; s > 0; s >>= 1) {
        if (t < s) sd[t] += sd[t + s];
        __syncthreads();
    }
    if (t == 0) bs[blockIdx.x] = sd[0];
}

__global__ void scan2_k(int* __restrict__ bs, int nb) {
    __shared__ int sd[512];
    int t = threadIdx.x;
    int v = (t < nb) ? bs[t] : 0;
    sd[t] = v;
    __syncthreads();
    for (int offm = 1; offm < 512; offm <<= 1) {
        int add = (t >= offm) ? sd[t - offm] : 0;
        __syncthreads();
        sd[t] += add;
        __syncthreads();
    }
    if (t < nb) bs[t] = sd[t] - v;   // exclusive
}

__global__ void scan3_k(const int* __restrict__ counts, const int* __restrict__ bs,
                        int* __restrict__ rowStart, int* __restrict__ cur, int Nn, int Ee) {
    __shared__ int sd[256];
    int t = threadIdx.x;
    int i = blockIdx.x * 256 + t;
    int v = (i < Nn) ? counts[i] : 0;
    sd[t] = v;
    __syncthreads();
    for (int offm = 1; offm < 256; offm <<= 1) {
        int add = (t >= offm) ? sd[t - offm] : 0;
        __syncthreads();
        sd[t] += add;
        __syncthreads();
    }
    int excl = sd[t] - v + bs[blockIdx.x];
    if (i < Nn) { rowStart[i] = excl; cur[i] = excl; }
    if (i == Nn) rowStart[i] = Ee;
}

__global__ void scatter_k(const int* __restrict__ srcI, const int* __restrict__ dstI,
                          int* __restrict__ cur, int* __restrict__ colI, int Ee) {
    int e = blockIdx.x * 256 + threadIdx.x;
    if (e < Ee) {
        int p = atomicAdd(&cur[srcI[e]], 1);
        colI[p] = dstI[e];
    }
}

// ---------------------------------------------------------------------------
// f16 MFMA GEMM: C[M x 256] = A[M x 256] @ B^T (B row-major [256][256], row =
// output col). 128x128 tile / 4 waves, BK=32, mfma_f32_16x16x32_f16.
// Fragment layouts mirror the m89/m97-verified bf16 pattern (dtype-indep C/D).
// OUTHALF=1: fp16 out via LDS-roundtrip coalesced stores. OUTHALF=0: fp32 out.
// ---------------------------------------------------------------------------
template <int OUTHALF, int RELU, int BIAS>
__global__ __launch_bounds__(256) void gemm_k(
    const __half* __restrict__ A, const __half* __restrict__ B,
    const float* __restrict__ bias, void* __restrict__ Cp, int M)
{
    __shared__ __align__(16) char smem[128 * 136 * 2];   // 34.8 KB
    short* As = (short*)smem;              // 128*40 shorts = 10240 B
    short* Bs = (short*)(smem + 10240);    // 128*40 shorts
    const int tid  = threadIdx.x;
    const int row0 = blockIdx.x * 128;
    const int col0 = blockIdx.y * 128;
    const int wave = tid >> 6, lane = tid & 63;
    const int m0w = (wave & 1) * 64;
    const int n0w = (wave >> 1) * 64;
    const int lm = lane & 15, lg = lane >> 4;

    f32x4 acc[4][4] = {};

    for (int k0 = 0; k0 < CDIM; k0 += 32) {
        #pragma unroll
        for (int l = 0; l < 2; ++l) {
            int c = tid + l * 256;
            int m = c >> 2, kc = c & 3;
            int gr = row0 + m;
            uint4 q = make_uint4(0u, 0u, 0u, 0u);
            if (gr < M) q = *(const uint4*)(A + (size_t)gr * CDIM + k0 + kc * 8);
            *(uint4*)(&As[m * 40 + kc * 8]) = q;
        }
        #pragma unroll
        for (int l = 0; l < 2; ++l) {
            int c = tid + l * 256;
            int nn = c >> 2, kc = c & 3;
            uint4 q = *(const uint4*)(B + (size_t)(col0 + nn) * CDIM + k0 + kc * 8);
            *(uint4*)(&Bs[nn * 40 + kc * 8]) = q;
        }
        __syncthreads();
        f16x8 af[4], bfr[4];
        #pragma unroll
        for (int i = 0; i < 4; ++i)
            af[i] = *(f16x8*)(&As[(m0w + i * 16 + lm) * 40 + lg * 8]);
        #pragma unroll
        for (int j = 0; j < 4; ++j)
            bfr[j] = *(f16x8*)(&Bs[(n0w + j * 16 + lm) * 40 + lg * 8]);
        #pragma unroll
        for (int i = 0; i < 4; ++i)
            #pragma unroll
            for (int j = 0; j < 4; ++j)
                acc[i][j] = __builtin_amdgcn_mfma_f32_16x16x32_f16(
                    af[i], bfr[j], acc[i][j], 0, 0, 0);
        __syncthreads();
    }

    if constexpr (OUTHALF) {
        // reorganize through LDS for coalesced 16B stores
        __half (*Cs)[136] = (__half(*)[136])smem;
        #pragma unroll
        for (int i = 0; i < 4; ++i)
            #pragma unroll
            for (int r = 0; r < 4; ++r) {
                int lr = m0w + i * 16 + lg * 4 + r;
                #pragma unroll
                for (int j = 0; j < 4; ++j) {
                    int lc = n0w + j * 16 + lm;
                    float t = acc[i][j][r];
                    if constexpr (BIAS) t += bias[col0 + lc];
                    if constexpr (RELU) t = fmaxf(t, 0.f);
                    Cs[lr][lc] = __float2half(t);
                }
            }
        __syncthreads();
        __half* C = (__half*)Cp;
        #pragma unroll
        for (int l = 0; l < 8; ++l) {
            int c = tid + l * 256;
            int rr = c >> 4, cc = c & 15;
            int gr = row0 + rr;
            if (gr < M)
                *(uint4*)(C + (size_t)gr * CDIM + col0 + cc * 8) = *(uint4*)(&Cs[rr][cc * 8]);
        }
    } else {
        float* C = (float*)Cp;
        #pragma unroll
        for (int i = 0; i < 4; ++i)
            #pragma unroll
            for (int r = 0; r < 4; ++r) {
                int grow = row0 + m0w + i * 16 + lg * 4 + r;
                if (grow < M) {
                    #pragma unroll
                    for (int j = 0; j < 4; ++j) {
                        int gcol = col0 + n0w + j * 16 + lm;
                        float t = acc[i][j][r];
                        if constexpr (BIAS) t += bias[gcol];
                        if constexpr (RELU) t = fmaxf(t, 0.f);
                        C[(size_t)grow * CDIM + gcol] = t;
                    }
                }
            }
    }
}

// ---------------------------------------------------------------------------
// Per-node attention scores from fp16 h. Block=256 = one node, wave = head.
// ---------------------------------------------------------------------------
__global__ __launch_bounds__(256) void scores_k(
    const __half* __restrict__ h,
    const float* __restrict__ a1w, const float* __restrict__ a1bias,
    const float* __restrict__ a2w, const float* __restrict__ a2bias,
    float* __restrict__ a1, float* __restrict__ a2)
{
    int n = blockIdx.x;
    int t = threadIdx.x;
    int head = t >> 6, d = t & 63;
    float hv = __half2float(h[(size_t)n * CDIM + t]);
    float s1 = hv * a1w[t];
    float s2 = hv * a2w[t];
    #pragma unroll
    for (int off = 32; off > 0; off >>= 1) {
        s1 += __shfl_xor(s1, off);
        s2 += __shfl_xor(s2, off);
    }
    if (d == 0) {
        a1[(size_t)n * H + head] = s1 + a1bias[head];
        a2[(size_t)n * H + head] = s2 + a2bias[head];
    }
}

// ---------------------------------------------------------------------------
// Edge aggregation v2: block = 4 waves per node; wave w takes edges s+w,
// s+w+4,... Each lane loads ushort4 (4 dims) -> one wave-instr covers the
// full 512B row. Cross-wave reduction in LDS.
// ---------------------------------------------------------------------------
__global__ __launch_bounds__(256) void agg_k(
    const __half* __restrict__ h, const float* __restrict__ a1, const float* __restrict__ a2,
    const int* __restrict__ rowStart, const int* __restrict__ colI,
    const float* __restrict__ bias, __half* __restrict__ outp, int relu)
{
    __shared__ float accL[4][64][4];
    __shared__ float denL[4][64];
    int n = blockIdx.x;
    int tid = threadIdx.x;
    int wave = tid >> 6, lane = tid & 63;
    int head = lane >> 4;                    // dims 4*lane..4*lane+3, head = lane>>4
    float a1n = a1[(size_t)n * H + head];
    int s = rowStart[n], e = rowStart[n + 1];
    float ac0 = 0.f, ac1 = 0.f, ac2 = 0.f, ac3 = 0.f, den = 0.f;
    for (int p = s + wave; p < e; p += 4) {
        int d = colI[p];
        float z = a1n + a2[(size_t)d * H + head];
        z = (z > 0.f) ? z : ALPHA * z;
        float sv = __expf(z);
        den += sv;
        ushort4 u = *(const ushort4*)(h + (size_t)d * CDIM + lane * 4);
        ac0 = fmaf(sv, __half2float(__ushort_as_half(u.x)), ac0);
        ac1 = fmaf(sv, __half2float(__ushort_as_half(u.y)), ac1);
        ac2 = fmaf(sv, __half2float(__ushort_as_half(u.z)), ac2);
        ac3 = fmaf(sv, __half2float(__ushort_as_half(u.w)), ac3);
    }
    accL[wave][lane][0] = ac0;
    accL[wave][lane][1] = ac1;
    accL[wave][lane][2] = ac2;
    accL[wave][lane][3] = ac3;
    denL[wave][lane] = den;
    __syncthreads();
    // thread t -> output dim t
    int l = tid >> 2, j = tid & 3;
    float a = accL[0][l][j] + accL[1][l][j] + accL[2][l][j] + accL[3][l][j];
    float dn = denL[0][l] + denL[1][l] + denL[2][l] + denL[3][l];
    dn = (dn > 0.f) ? dn : 1.f;
    float r = a / dn + bias[tid];
    if (relu) r = fmaxf(r, 0.f);
    outp[(size_t)n * CDIM + tid] = __float2half(r);
}

// ---------------------------------------------------------------------------
// Classifier: one wave per node; output dtype per flag (R2/R4-proven).
// ---------------------------------------------------------------------------
__global__ __launch_bounds__(256) void cls_k(
    const float* __restrict__ feat, const float* __restrict__ Wcls,
    const float* __restrict__ bcls, void* __restrict__ out, int Nn,
    const int* __restrict__ flagp)
{
    int gtid = blockIdx.x * 256 + threadIdx.x;
    int n = gtid >> 6;
    int lane = threadIdx.x & 63;
    if (n >= Nn) return;
    const float* f = feat + (size_t)n * CDIM;
    float p0 = 0.f, p1 = 0.f, p2 = 0.f, p3 = 0.f;
    for (int k = lane; k < CDIM; k += 64) {
        float fv = f[k];
        p0 = fmaf(fv, Wcls[0 * CDIM + k], p0);
        p1 = fmaf(fv, Wcls[1 * CDIM + k], p1);
        p2 = fmaf(fv, Wcls[2 * CDIM + k], p2);
        p3 = fmaf(fv, Wcls[3 * CDIM + k], p3);
    }
    #pragma unroll
    for (int off = 32; off > 0; off >>= 1) {
        p0 += __shfl_xor(p0, off);
        p1 += __shfl_xor(p1, off);
        p2 += __shfl_xor(p2, off);
        p3 += __shfl_xor(p3, off);
    }
    if (lane < OUTC) {
        float pv = (lane == 0) ? p0 : (lane == 1) ? p1 : (lane == 2) ? p2 : p3;
        pv += bcls[lane];
        if (*flagp) ((__hip_bfloat16*)out)[(size_t)n * OUTC + lane] = __float2bfloat16(pv);
        else        ((float*)out)[(size_t)n * OUTC + lane] = pv;
    }
}

// ---------------------------------------------------------------------------
extern "C" void kernel_launch(void* const* d_in, const int* in_sizes, int n_in,
                              void* d_out, int out_size, void* d_ws, size_t ws_size,
                              hipStream_t stream)
{
    const void* x  = d_in[0];
    const int*  ei = (const int*)d_in[1];

    const int Nn = in_sizes[0] / CDIM;   // 100000
    const int Ee = in_sizes[1] / 2;      // 1600000
    const int* srcI = ei;
    const int* dstI = ei + Ee;

    char* wsp = (char*)d_ws;
    size_t off = 0;
    auto alloc = [&](size_t bytes) -> void* {
        void* p = wsp + off;
        off += (bytes + 255) & ~(size_t)255;
        return p;
    };
    // Buffer rotation: gemm1: xh->hA; agg1: hA->hB; gemm2: hB->xh;
    // agg2: xh->hB; collator: hB->bufA(fp32, aliases xh+hA, both dead).
    __half* xh  = (__half*)alloc((size_t)Nn * CDIM * 2);  // 51.2 MB
    __half* hA  = (__half*)alloc((size_t)Nn * CDIM * 2);  // 51.2 MB
    __half* hB  = (__half*)alloc((size_t)Nn * CDIM * 2);  // 51.2 MB
    float*  bufA = (float*)xh;                            // 102.4 MB alias (xh+hA)
    float*  a1v       = (float*)alloc((size_t)Nn * H * 4);
    float*  a2v       = (float*)alloc((size_t)Nn * H * 4);
    int*    rowStart  = (int*)alloc((size_t)(Nn + 1) * 4);
    int*    cursor    = (int*)alloc((size_t)Nn * 4);
    int*    colI      = (int*)alloc((size_t)Ee * 4);      // 6.4 MB
    int*    blockSums = (int*)alloc(512 * 4);
    int*    flag      = (int*)alloc(256);
    float*  wconv     = (float*)alloc((size_t)200000 * 4);
    __half* wh        = (__half*)alloc((size_t)200000 * 2);
    (void)ws_size; (void)n_in; (void)out_size;

    // dtype detect + weight conversion (proven machinery)
    detect_k<<<1, 256, 0, stream>>>((const uint32_t*)x, flag);
    WPtrs wp;
    int woff = 0;
    for (int i = 0; i < NW; ++i) {
        wp.p[i] = d_in[2 + i];
        wp.sz[i] = in_sizes[2 + i];
        wp.off[i] = woff;
        woff += in_sizes[2 + i];
    }
    {
        dim3 cgrid(256, NW);
        convert_k<<<cgrid, 256, 0, stream>>>(wp, wconv, wh, flag);
    }
    const float*  a11wf = wconv + wp.off[1];
    const float*  a11bf = wconv + wp.off[2];
    const float*  a12wf = wconv + wp.off[3];
    const float*  a12bf = wconv + wp.off[4];
    const float*  b1f   = wconv + wp.off[5];
    const float*  a21wf = wconv + wp.off[7];
    const float*  a21bf = wconv + wp.off[8];
    const float*  a22wf = wconv + wp.off[9];
    const float*  a22bf = wconv + wp.off[10];
    const float*  b2f   = wconv + wp.off[11];
    const float*  bcf   = wconv + wp.off[13];
    const float*  Wclsf = wconv + wp.off[14];
    const float*  bclsf = wconv + wp.off[15];
    const __half* W1h   = wh + wp.off[0];
    const __half* W2h   = wh + wp.off[6];
    const __half* Wch   = wh + wp.off[12];

    const int NB = (Nn + 255) / 256;   // 391 (fits scan2's 512)
    const int EB = (Ee + 255) / 256;
    const int C4 = (Nn * CDIM / 4 + 255) / 256;

    // x -> fp16
    castx_k<<<C4, 256, 0, stream>>>(x, xh, flag, Nn * CDIM / 4);

    // CSR build
    hipMemsetAsync(cursor, 0, (size_t)Nn * 4, stream);
    hist_k<<<EB, 256, 0, stream>>>(srcI, cursor, Ee);
    scan1_k<<<NB, 256, 0, stream>>>(cursor, blockSums, Nn);
    scan2_k<<<1, 512, 0, stream>>>(blockSums, NB);
    scan3_k<<<NB, 256, 0, stream>>>(cursor, blockSums, rowStart, cursor, Nn, Ee);
    scatter_k<<<EB, 256, 0, stream>>>(srcI, dstI, cursor, colI, Ee);

    dim3 ggrid((Nn + 127) / 128, CDIM / 128);   // (782, 2)

    // Layer 1
    gemm_k<1, 0, 0><<<ggrid, 256, 0, stream>>>(xh, W1h, nullptr, hA, Nn);
    scores_k<<<Nn, 256, 0, stream>>>(hA, a11wf, a11bf, a12wf, a12bf, a1v, a2v);
    agg_k<<<Nn, 256, 0, stream>>>(hA, a1v, a2v, rowStart, colI, b1f, hB, 1);

    // Layer 2 (gemm2 writes xh — x no longer needed)
    gemm_k<1, 0, 0><<<ggrid, 256, 0, stream>>>(hB, W2h, nullptr, xh, Nn);
    scores_k<<<Nn, 256, 0, stream>>>(xh, a21wf, a21bf, a22wf, a22bf, a1v, a2v);
    agg_k<<<Nn, 256, 0, stream>>>(xh, a1v, a2v, rowStart, colI, b2f, hB, 0);

    // Collator (fp32 out into alias over dead xh+hA) + classifier
    gemm_k<0, 1, 1><<<ggrid, 256, 0, stream>>>(hB, Wch, bcf, bufA, Nn);
    cls_k<<<(Nn * 64 + 255) / 256, 256, 0, stream>>>(bufA, Wclsf, bclsf,
                                                     d_out, Nn, flag);
}